// Round 1
// baseline (172.353 us; speedup 1.0000x reference)
//
#include <hip/hip_runtime.h>
#include <hip/hip_bf16.h>

namespace {

constexpr int kS  = 2048;
constexpr int kD  = 128;
constexpr int kQB = 128;          // q-rows per block
constexpr int kWQ = 32;           // q-rows per wave
constexpr int kKB = 64;           // kv-rows per tile
constexpr int kNT = kS / kKB;     // 32 tiles
constexpr int kKStr = kD + 8;     // 136  (K lds row stride, bf16 elems)
constexpr int kVStr = kKB + 8;    // 72   (V^T lds row stride)
constexpr int kPStr = kKB + 8;    // 72

typedef __attribute__((ext_vector_type(8))) short bf16x8;
typedef __attribute__((ext_vector_type(4))) float f32x4;

__device__ inline unsigned short f2bf(float f) {
  __hip_bfloat16 h = __float2bfloat16(f);
  return __builtin_bit_cast(unsigned short, h);
}

__global__ __launch_bounds__(256, 1)
void attn_fwd(const float* __restrict__ Q, const float* __restrict__ K,
              const float* __restrict__ V, float* __restrict__ O)
{
  __shared__ unsigned short Klds[2][kKB][kKStr];   // [k][d]
  __shared__ unsigned short Vlds[2][kD][kVStr];    // [d][k] transposed, swizzled
  __shared__ unsigned short Plds[4][kWQ][kPStr];   // per-wave P tile [q][k]

  const int tid  = threadIdx.x;
  const int wv   = tid >> 6;
  const int lane = tid & 63;
  const int l15  = lane & 15;
  const int grp  = lane >> 4;

  // XCD-locality: pin 2 batches per XCD (K/V working set = 4 MB = one L2)
  const int bid   = blockIdx.x;
  const int xcd   = bid & 7;
  const int slot  = bid >> 3;              // 0..31
  const int batch = xcd * 2 + (slot >> 4); // 0..15
  const int qtile = slot & 15;

  const float* Qb = Q + (size_t)batch * kS * kD;
  const float* Kb = K + (size_t)batch * kS * kD;
  const float* Vb = V + (size_t)batch * kS * kD;
  float*       Ob = O + (size_t)batch * kS * kD;

  const int qbase = qtile * kQB + wv * kWQ;

  // ---- Q fragments, scaled by (1/sqrt(D)) * log2(e)  [softmax in log2 domain]
  constexpr float kQScale = 0.08838834764831845f * 1.4426950408889634f;
  bf16x8 qf[2][4];
#pragma unroll
  for (int qs = 0; qs < 2; ++qs) {
#pragma unroll
    for (int c = 0; c < 4; ++c) {
      const float* p = Qb + (size_t)(qbase + qs * 16 + l15) * kD + c * 32 + grp * 8;
      float4 a = *reinterpret_cast<const float4*>(p);
      float4 b = *reinterpret_cast<const float4*>(p + 4);
      bf16x8 f;
      f[0] = (short)f2bf(a.x * kQScale);
      f[1] = (short)f2bf(a.y * kQScale);
      f[2] = (short)f2bf(a.z * kQScale);
      f[3] = (short)f2bf(a.w * kQScale);
      f[4] = (short)f2bf(b.x * kQScale);
      f[5] = (short)f2bf(b.y * kQScale);
      f[6] = (short)f2bf(b.z * kQScale);
      f[7] = (short)f2bf(b.w * kQScale);
      qf[qs][c] = f;
    }
  }

  // ---- staging registers (held across compute for latency hiding)
  float4 kreg[8];
  float4 vreg0[4], vreg1[4];

  auto load_tile = [&](int t) {
    const float* ks = Kb + (size_t)t * kKB * kD;
#pragma unroll
    for (int i = 0; i < 8; ++i) {
      int idx = i * 256 + tid;                       // 0..2047
      kreg[i] = *reinterpret_cast<const float4*>(ks + (size_t)(idx >> 5) * kD + (idx & 31) * 4);
    }
    const float* vs = Vb + (size_t)t * kKB * kD;
#pragma unroll
    for (int i = 0; i < 4; ++i) {
      int u = i * 256 + tid;                         // 0..1023
      int kp = u >> 5, d4 = u & 31;
      vreg0[i] = *reinterpret_cast<const float4*>(vs + (size_t)(2 * kp) * kD + d4 * 4);
      vreg1[i] = *reinterpret_cast<const float4*>(vs + (size_t)(2 * kp + 1) * kD + d4 * 4);
    }
  };

  auto store_tile = [&](int b) {
#pragma unroll
    for (int i = 0; i < 8; ++i) {
      int idx = i * 256 + tid;
      ushort4 c;
      c.x = f2bf(kreg[i].x);
      c.y = f2bf(kreg[i].y);
      c.z = f2bf(kreg[i].z);
      c.w = f2bf(kreg[i].w);
      *reinterpret_cast<ushort4*>(&Klds[b][idx >> 5][(idx & 31) * 4]) = c;
    }
#pragma unroll
    for (int i = 0; i < 4; ++i) {
      int u = i * 256 + tid;
      int kp = u >> 5, d4 = u & 31;
      float a0[4] = {vreg0[i].x, vreg0[i].y, vreg0[i].z, vreg0[i].w};
      float a1[4] = {vreg1[i].x, vreg1[i].y, vreg1[i].z, vreg1[i].w};
#pragma unroll
      for (int j = 0; j < 4; ++j) {
        int d = d4 * 4 + j;
        int ksw = (2 * kp) ^ (8 * ((d >> 3) & 7));   // XOR swizzle: 4-way writes, 2-way reads
        ushort2 c;
        c.x = f2bf(a0[j]);
        c.y = f2bf(a1[j]);
        *reinterpret_cast<ushort2*>(&Vlds[b][d][ksw]) = c;
      }
    }
  };

  // ---- flash state
  f32x4 acc[2][8];
  float mrun[2][4], lrun[2][4];
#pragma unroll
  for (int qs = 0; qs < 2; ++qs)
#pragma unroll
    for (int r = 0; r < 4; ++r) { mrun[qs][r] = -1e30f; lrun[qs][r] = 0.f; }
#pragma unroll
  for (int qs = 0; qs < 2; ++qs)
#pragma unroll
    for (int dt = 0; dt < 8; ++dt) acc[qs][dt] = {0.f, 0.f, 0.f, 0.f};

  load_tile(0);
  store_tile(0);
  __syncthreads();

  for (int t = 0; t < kNT; ++t) {
    const int cur = t & 1;
    if (t + 1 < kNT) load_tile(t + 1);   // issue early; lands during compute

    // ---- QK^T : S[q][k], D-layout col=l15=k_local, row=4*grp+reg=q_local
    f32x4 sc[2][4];
#pragma unroll
    for (int qs = 0; qs < 2; ++qs)
#pragma unroll
      for (int kt = 0; kt < 4; ++kt) sc[qs][kt] = {0.f, 0.f, 0.f, 0.f};
#pragma unroll
    for (int kt = 0; kt < 4; ++kt) {
#pragma unroll
      for (int c = 0; c < 4; ++c) {
        bf16x8 kf = *reinterpret_cast<const bf16x8*>(&Klds[cur][kt * 16 + l15][c * 32 + grp * 8]);
        sc[0][kt] = __builtin_amdgcn_mfma_f32_16x16x32_bf16(qf[0][c], kf, sc[0][kt], 0, 0, 0);
        sc[1][kt] = __builtin_amdgcn_mfma_f32_16x16x32_bf16(qf[1][c], kf, sc[1][kt], 0, 0, 0);
      }
    }

    // ---- online softmax (log2 domain; 16-lane row groups)
    float pr[2][4][4];
#pragma unroll
    for (int qs = 0; qs < 2; ++qs) {
#pragma unroll
      for (int r = 0; r < 4; ++r) {
        float mt = fmaxf(fmaxf(sc[qs][0][r], sc[qs][1][r]),
                         fmaxf(sc[qs][2][r], sc[qs][3][r]));
        mt = fmaxf(mt, __shfl_xor(mt, 1));
        mt = fmaxf(mt, __shfl_xor(mt, 2));
        mt = fmaxf(mt, __shfl_xor(mt, 4));
        mt = fmaxf(mt, __shfl_xor(mt, 8));
        const float mold = mrun[qs][r];
        const float mnew = fmaxf(mold, mt);
        const float corr = exp2f(mold - mnew);
        mrun[qs][r] = mnew;
        float rs = 0.f;
#pragma unroll
        for (int kt = 0; kt < 4; ++kt) {
          float p = exp2f(sc[qs][kt][r] - mnew);
          pr[qs][kt][r] = p;
          rs += p;
        }
        rs += __shfl_xor(rs, 1);
        rs += __shfl_xor(rs, 2);
        rs += __shfl_xor(rs, 4);
        rs += __shfl_xor(rs, 8);
        lrun[qs][r] = lrun[qs][r] * corr + rs;
#pragma unroll
        for (int dt = 0; dt < 8; ++dt) acc[qs][dt][r] *= corr;
      }
    }

    // ---- P -> LDS (bf16), D-layout scatter
#pragma unroll
    for (int qs = 0; qs < 2; ++qs)
#pragma unroll
      for (int kt = 0; kt < 4; ++kt)
#pragma unroll
        for (int r = 0; r < 4; ++r)
          Plds[wv][qs * 16 + grp * 4 + r][kt * 16 + l15] = f2bf(pr[qs][kt][r]);

    // ---- P·V : acc[q][d] += P[q][k] V[k][d]
#pragma unroll
    for (int kc = 0; kc < 2; ++kc) {
      bf16x8 pf0 = *reinterpret_cast<const bf16x8*>(&Plds[wv][l15][kc * 32 + grp * 8]);
      bf16x8 pf1 = *reinterpret_cast<const bf16x8*>(&Plds[wv][16 + l15][kc * 32 + grp * 8]);
#pragma unroll
      for (int dt = 0; dt < 8; ++dt) {
        const int d = dt * 16 + l15;
        const int kcol = (kc * 32 + grp * 8) ^ (8 * ((d >> 3) & 7));
        bf16x8 vf = *reinterpret_cast<const bf16x8*>(&Vlds[cur][d][kcol]);
        acc[0][dt] = __builtin_amdgcn_mfma_f32_16x16x32_bf16(pf0, vf, acc[0][dt], 0, 0, 0);
        acc[1][dt] = __builtin_amdgcn_mfma_f32_16x16x32_bf16(pf1, vf, acc[1][dt], 0, 0, 0);
      }
    }

    if (t + 1 < kNT) store_tile(cur ^ 1);  // regs loaded at loop top -> other buffer
    __syncthreads();
  }

  // ---- epilogue: O = acc / l
#pragma unroll
  for (int qs = 0; qs < 2; ++qs) {
#pragma unroll
    for (int r = 0; r < 4; ++r) {
      const float inv = 1.0f / lrun[qs][r];
      const int row = qbase + qs * 16 + grp * 4 + r;
#pragma unroll
      for (int dt = 0; dt < 8; ++dt)
        Ob[(size_t)row * kD + dt * 16 + l15] = acc[qs][dt][r] * inv;
    }
  }
}

} // namespace

extern "C" void kernel_launch(void* const* d_in, const int* in_sizes, int n_in,
                              void* d_out, int out_size, void* d_ws, size_t ws_size,
                              hipStream_t stream) {
  const float* Q = (const float*)d_in[0];
  const float* K = (const float*)d_in[1];
  const float* V = (const float*)d_in[2];
  float* O = (float*)d_out;
  (void)in_sizes; (void)n_in; (void)out_size; (void)d_ws; (void)ws_size;
  dim3 grid(256), block(256);
  hipLaunchKernelGGL(attn_fwd, grid, block, 0, stream, Q, K, V, O);
}

// Round 2
// 76.427 us; speedup vs baseline: 2.2551x; 2.2551x over previous
//
#include <hip/hip_runtime.h>
#include <hip/hip_bf16.h>

namespace {

constexpr int kS  = 2048;
constexpr int kD  = 128;
constexpr int kQB = 128;          // q-rows per block
constexpr int kKB = 64;           // kv-rows per tile
constexpr int kNT = kS / kKB;     // 32 tiles
constexpr int kKStr = kD + 8;     // 136 (K lds row stride, ushorts)
constexpr int kVStr = kKB + 8;    // 72  (V^T lds row stride)
constexpr int kPStr = 40;         // 32 k + 8 pad; mult of 8 -> 16B-aligned b128 rows

constexpr int kKBytes = 2 * kKB * kKStr * 2;     // 34816
constexpr int kVBytes = 2 * kD * kVStr * 2;      // 36864
constexpr int kPBytes = 16 * 16 * kPStr * 2;     // 20480
constexpr int kSmemBytes = kKBytes + kVBytes + kPBytes;  // 92160

typedef __attribute__((ext_vector_type(8))) short bf16x8;
typedef __attribute__((ext_vector_type(4))) float f32x4;

__device__ inline unsigned short f2bf(float f) {
  return __builtin_bit_cast(unsigned short, __float2bfloat16(f));
}
__device__ inline float fexp2(float x) { return __builtin_amdgcn_exp2f(x); }

// DPP lane rotate within 16-lane rows (never crosses row boundary).
template <int CTRL>
__device__ inline float dpp_mov(float x) {
  int r = __builtin_amdgcn_update_dpp(0, __builtin_bit_cast(int, x), CTRL, 0xf, 0xf, false);
  return __builtin_bit_cast(float, r);
}
// Full 16-lane reduction via xor1, xor2 (quad_perm) + ror4, ror8.
__device__ inline float row16_max(float x) {
  x = fmaxf(x, dpp_mov<0xB1>(x));    // quad_perm [1,0,3,2]
  x = fmaxf(x, dpp_mov<0x4E>(x));    // quad_perm [2,3,0,1]
  x = fmaxf(x, dpp_mov<0x124>(x));   // row_ror:4
  x = fmaxf(x, dpp_mov<0x128>(x));   // row_ror:8
  return x;
}
__device__ inline float row16_sum(float x) {
  x += dpp_mov<0xB1>(x);
  x += dpp_mov<0x4E>(x);
  x += dpp_mov<0x124>(x);
  x += dpp_mov<0x128>(x);
  return x;
}

__global__ __launch_bounds__(1024)
void attn_fwd(const float* __restrict__ Q, const float* __restrict__ K,
              const float* __restrict__ V, float* __restrict__ O)
{
  __shared__ __align__(16) unsigned char smem[kSmemBytes];
  auto Klds = reinterpret_cast<unsigned short (*)[kKB][kKStr]>(smem);            // [2][64][136]
  auto Vlds = reinterpret_cast<unsigned short (*)[kD][kVStr]>(smem + kKBytes);   // [2][128][72]
  auto Plds = reinterpret_cast<unsigned short (*)[kPStr]>(smem + kKBytes + kVBytes); // [256][40]

  const int tid  = threadIdx.x;
  const int wv   = tid >> 6;        // 0..15
  const int qw   = wv & 7;          // q-wave
  const int g    = wv >> 3;         // k-half group
  const int lane = tid & 63;
  const int l15  = lane & 15;
  const int grp  = lane >> 4;

  // XCD-locality: 2 batches per XCD
  const int bid   = blockIdx.x;
  const int xcd   = bid & 7;
  const int slot  = bid >> 3;
  const int batch = xcd * 2 + (slot >> 4);
  const int qtile = slot & 15;

  const float* Qb = Q + (size_t)batch * kS * kD;
  const float* Kb = K + (size_t)batch * kS * kD;
  const float* Vb = V + (size_t)batch * kS * kD;
  float*       Ob = O + (size_t)batch * kS * kD;

  const int qrow0 = qtile * kQB + qw * 16;

  // ---- Q fragment (16 rows per wave), scale*log2e folded in
  constexpr float kQScale = 0.08838834764831845f * 1.4426950408889634f;
  bf16x8 qf[4];
#pragma unroll
  for (int c = 0; c < 4; ++c) {
    const float* p = Qb + (size_t)(qrow0 + l15) * kD + c * 32 + grp * 8;
    float4 a = *reinterpret_cast<const float4*>(p);
    float4 b = *reinterpret_cast<const float4*>(p + 4);
    bf16x8 f;
    f[0] = (short)f2bf(a.x * kQScale);
    f[1] = (short)f2bf(a.y * kQScale);
    f[2] = (short)f2bf(a.z * kQScale);
    f[3] = (short)f2bf(a.w * kQScale);
    f[4] = (short)f2bf(b.x * kQScale);
    f[5] = (short)f2bf(b.y * kQScale);
    f[6] = (short)f2bf(b.z * kQScale);
    f[7] = (short)f2bf(b.w * kQScale);
    qf[c] = f;
  }

  // ---- staging registers
  float4 kreg[2];
  float4 vreg0, vreg1;

  auto load_tile = [&](int t) {
    const float* ks = Kb + (size_t)t * kKB * kD;
#pragma unroll
    for (int i = 0; i < 2; ++i) {
      int idx = i * 1024 + tid;     // 0..2047
      kreg[i] = *reinterpret_cast<const float4*>(ks + (size_t)(idx >> 5) * kD + (idx & 31) * 4);
    }
    const float* vs = Vb + (size_t)t * kKB * kD;
    const int kp = tid >> 5, d4 = tid & 31;
    vreg0 = *reinterpret_cast<const float4*>(vs + (size_t)(2 * kp) * kD + d4 * 4);
    vreg1 = *reinterpret_cast<const float4*>(vs + (size_t)(2 * kp + 1) * kD + d4 * 4);
  };

  auto store_tile = [&](int b) {
#pragma unroll
    for (int i = 0; i < 2; ++i) {
      int idx = i * 1024 + tid;
      ushort4 c;
      c.x = f2bf(kreg[i].x);
      c.y = f2bf(kreg[i].y);
      c.z = f2bf(kreg[i].z);
      c.w = f2bf(kreg[i].w);
      *reinterpret_cast<ushort4*>(&Klds[b][idx >> 5][(idx & 31) * 4]) = c;
    }
    const int kp = tid >> 5, d4 = tid & 31;
    float a0[4] = {vreg0.x, vreg0.y, vreg0.z, vreg0.w};
    float a1[4] = {vreg1.x, vreg1.y, vreg1.z, vreg1.w};
#pragma unroll
    for (int j = 0; j < 4; ++j) {
      int d = d4 * 4 + j;
      int ksw = (2 * kp) ^ (8 * ((d >> 3) & 7));
      ushort2 c;
      c.x = f2bf(a0[j]);
      c.y = f2bf(a1[j]);
      *reinterpret_cast<ushort2*>(&Vlds[b][d][ksw]) = c;
    }
  };

  // ---- flash state (per wave: 16 q-rows x k-half)
  f32x4 acc[8];
  float mrun[4], lrun[4];
#pragma unroll
  for (int r = 0; r < 4; ++r) { mrun[r] = -1e30f; lrun[r] = 0.f; }
#pragma unroll
  for (int dt = 0; dt < 8; ++dt) acc[dt] = {0.f, 0.f, 0.f, 0.f};

  load_tile(0);
  store_tile(0);
  __syncthreads();

  for (int t = 0; t < kNT; ++t) {
    const int cur = t & 1;
    if (t + 1 < kNT) load_tile(t + 1);      // issue early (T14)

    // ---- QK^T on this wave's k-half: S[q=grp*4+r][k=ktl*16+l15]
    f32x4 sc[2];
    sc[0] = {0.f, 0.f, 0.f, 0.f};
    sc[1] = {0.f, 0.f, 0.f, 0.f};
    __builtin_amdgcn_s_setprio(1);
#pragma unroll
    for (int ktl = 0; ktl < 2; ++ktl) {
#pragma unroll
      for (int c = 0; c < 4; ++c) {
        bf16x8 kf = *reinterpret_cast<const bf16x8*>(
            &Klds[cur][g * 32 + ktl * 16 + l15][c * 32 + grp * 8]);
        sc[ktl] = __builtin_amdgcn_mfma_f32_16x16x32_bf16(qf[c], kf, sc[ktl], 0, 0, 0);
      }
    }
    __builtin_amdgcn_s_setprio(0);

    // ---- online softmax (log2 domain), DPP 16-lane reductions
    float mt[4];
#pragma unroll
    for (int r = 0; r < 4; ++r)
      mt[r] = row16_max(fmaxf(sc[0][r], sc[1][r]));

    float growth = fmaxf(fmaxf(mt[0] - mrun[0], mt[1] - mrun[1]),
                         fmaxf(mt[2] - mrun[2], mt[3] - mrun[3]));
    if (!__all(growth <= 8.0f)) {           // T13 defer-max
#pragma unroll
      for (int r = 0; r < 4; ++r) {
        const float mnew = fmaxf(mrun[r], mt[r]);
        const float corr = fexp2(mrun[r] - mnew);
        mrun[r] = mnew;
        lrun[r] *= corr;
#pragma unroll
        for (int dt = 0; dt < 8; ++dt) acc[dt][r] *= corr;
      }
    }

    float pr[2][4];
#pragma unroll
    for (int r = 0; r < 4; ++r) {
      pr[0][r] = fexp2(sc[0][r] - mrun[r]);
      pr[1][r] = fexp2(sc[1][r] - mrun[r]);
      lrun[r] += row16_sum(pr[0][r] + pr[1][r]);
    }

    // ---- P -> LDS (per-wave region, no barrier needed)
#pragma unroll
    for (int ktl = 0; ktl < 2; ++ktl)
#pragma unroll
      for (int r = 0; r < 4; ++r)
        Plds[wv * 16 + grp * 4 + r][ktl * 16 + l15] = f2bf(pr[ktl][r]);

    // ---- P·V over this wave's k-half
    bf16x8 pf = *reinterpret_cast<const bf16x8*>(&Plds[wv * 16 + l15][grp * 8]);
    __builtin_amdgcn_s_setprio(1);
#pragma unroll
    for (int dt = 0; dt < 8; ++dt) {
      const int d = dt * 16 + l15;
      const int kcol = (g * 32 + grp * 8) ^ (8 * ((d >> 3) & 7));
      bf16x8 vf = *reinterpret_cast<const bf16x8*>(&Vlds[cur][d][kcol]);
      acc[dt] = __builtin_amdgcn_mfma_f32_16x16x32_bf16(pf, vf, acc[dt], 0, 0, 0);
    }
    __builtin_amdgcn_s_setprio(0);

    if (t + 1 < kNT) store_tile(cur ^ 1);
    __syncthreads();
  }

  // ---- merge the two k-half groups (overlay scratch on K/V staging region)
  float* mscratch = reinterpret_cast<float*>(smem);            // 8 qw x 16 q x 128 d = 64KB
  float* mlrow    = reinterpret_cast<float*>(smem + 65536);    // 8 qw x {16 m, 16 l}

  if (g == 1) {
#pragma unroll
    for (int r = 0; r < 4; ++r) {
      const int q = grp * 4 + r;
#pragma unroll
      for (int dt = 0; dt < 8; ++dt)
        mscratch[qw * 2048 + q * 128 + dt * 16 + l15] = acc[dt][r];
      if (l15 == 0) {
        mlrow[qw * 32 + q]      = mrun[r];
        mlrow[qw * 32 + 16 + q] = lrun[r];
      }
    }
  }
  __syncthreads();
  if (g == 0) {
#pragma unroll
    for (int r = 0; r < 4; ++r) {
      const int q = grp * 4 + r;
      const float m1 = mlrow[qw * 32 + q];
      const float l1 = mlrow[qw * 32 + 16 + q];
      const float mm = fmaxf(mrun[r], m1);
      const float w0 = fexp2(mrun[r] - mm);
      const float w1 = fexp2(m1 - mm);
      const float inv = 1.0f / (lrun[r] * w0 + l1 * w1);
      const int row = qrow0 + q;
#pragma unroll
      for (int dt = 0; dt < 8; ++dt) {
        const float o1 = mscratch[qw * 2048 + q * 128 + dt * 16 + l15];
        Ob[(size_t)row * kD + dt * 16 + l15] = (acc[dt][r] * w0 + o1 * w1) * inv;
      }
    }
  }
}

} // namespace

extern "C" void kernel_launch(void* const* d_in, const int* in_sizes, int n_in,
                              void* d_out, int out_size, void* d_ws, size_t ws_size,
                              hipStream_t stream) {
  const float* Q = (const float*)d_in[0];
  const float* K = (const float*)d_in[1];
  const float* V = (const float*)d_in[2];
  float* O = (float*)d_out;
  (void)in_sizes; (void)n_in; (void)out_size; (void)d_ws; (void)ws_size;
  dim3 grid(256), block(1024);
  hipLaunchKernelGGL(attn_fwd, grid, block, 0, stream, Q, K, V, O);
}